// Round 16
// baseline (104.575 us; speedup 1.0000x reference)
//
#include <hip/hip_runtime.h>
#include <hip/hip_bf16.h>
#include <cfloat>

#define NPTS 16384
#define NT16 1024           // 16-point tiles per side
#define R 8                 // A-tiles per wave (a=32, m=32 regs)
#define BS 16               // B-chunk splits
#define CPT (NT16 / BS)     // 64 B-tiles per chunk

typedef short short8  __attribute__((ext_vector_type(8)));
typedef float f32x4   __attribute__((ext_vector_type(4)));

__device__ inline short bf16s(float x) {
    __hip_bfloat16 h = __float2bfloat16(x);   // RNE
    return *reinterpret_cast<short*>(&h);
}
__device__ inline float bf16f(short s) {
    __hip_bfloat16 h = *reinterpret_cast<__hip_bfloat16*>(&s);
    return __bfloat162float(h);
}

// 16x16x32 fragments. Slot map s = 8*(lane>>4)+j (A and B symmetric).
// A slots 0..15: [ahx ahy ahz alx aly alz ahx ahy | ahz alx aly alz sqa_h sqa_l 1 1]
// B slots 0..15: [bhx bhy bhz bhx bhy bhz blx bly | blz blx bly blz 1 1 sqb_h sqb_l]
// (b* = hi/lo split of -2*coord). slots 16..31 = 0.
// Sum = (ah+al)(bh+bl) + |a|^2 + |b|^2 = d^2 EXACTLY (all 4 cross terms kept).
// Also initializes minsq (0x7F7F7F7F) and out[0]=0.
__global__ __launch_bounds__(256) void pack_kernel(
    const float* __restrict__ target, const float* __restrict__ output,
    short8* __restrict__ afrag, short8* __restrict__ bfrag,
    int* __restrict__ minsq, float* __restrict__ out)
{
    int t = blockIdx.x * 256 + threadIdx.x;   // [0, 2*1024*64)
    if (t < 2 * NPTS) minsq[t] = 0x7F7F7F7F;
    if (t == 0) out[0] = 0.0f;

    int lane = t & 63;
    int tile = (t >> 6) & (NT16 - 1);
    int dir  = t >> 16;
    const float* __restrict__ A = dir ? target : output;  // query side
    const float* __restrict__ B = dir ? output : target;  // candidate side
    int p = tile * 16 + (lane & 15);
    int g = lane >> 4;                 // k-slot group 0..3
    int idx = (dir * NT16 + tile) * 64 + lane;
    const short one = 0x3F80;
    short8 z = {0, 0, 0, 0, 0, 0, 0, 0};

    {
        float x = A[3 * p], y = A[3 * p + 1], z3 = A[3 * p + 2];
        short hx = bf16s(x), hy = bf16s(y), hz = bf16s(z3);
        short lx = bf16s(x - bf16f(hx)), ly = bf16s(y - bf16f(hy)), lz = bf16s(z3 - bf16f(hz));
        float sq = fmaf(x, x, fmaf(y, y, z3 * z3));
        short sh = bf16s(sq), sl = bf16s(sq - bf16f(sh));
        short8 g0 = { hx, hy, hz, lx, ly, lz, hx, hy };
        short8 g1 = { hz, lx, ly, lz, sh, sl, one, one };
        afrag[idx] = g == 0 ? g0 : (g == 1 ? g1 : z);
    }
    {
        float x = B[3 * p], y = B[3 * p + 1], z3 = B[3 * p + 2];
        float nx = -2.f * x, ny = -2.f * y, nz = -2.f * z3;
        short hx = bf16s(nx), hy = bf16s(ny), hz = bf16s(nz);
        short lx = bf16s(nx - bf16f(hx)), ly = bf16s(ny - bf16f(hy)), lz = bf16s(nz - bf16f(hz));
        float sq = fmaf(x, x, fmaf(y, y, z3 * z3));
        short sh = bf16s(sq), sl = bf16s(sq - bf16f(sh));
        short8 g0 = { hx, hy, hz, hx, hy, hz, lx, ly };
        short8 g1 = { hz, lx, ly, lz, one, one, sh, sl };
        // careful: B g1 slot order must mirror A's product pairing:
        // s8: blz (pairs ahz), s9..11: blx,bly,blz (pair alx,aly,alz),
        // s12,s13: 1,1 (pair sqa_h,sqa_l), s14,s15: sqb_h,sqb_l (pair 1,1)
        short8 g1b = { hz /*blz? no*/, lx, ly, lz, one, one, sh, sl };
        (void)g1; (void)g1b;
        short8 bg1 = { lz, lx, ly, lz, one, one, sh, sl };
        // s8 must be blz: element 0 of g1 group = lz ✔ (bg1)
        bfrag[idx] = g == 0 ? g0 : (g == 1 ? bg1 : z);
    }
}

// 256-thread blocks (4 waves). Wave: R=8 A-tiles (16x16) vs 64-tile B chunk
// from L2, 4 loads in flight, fence-free. Small C/D (4 regs) keeps everything
// in VGPRs -> no accvgpr churn, 4 waves/SIMD resident.
// C/D layout (m89): col=lane&15, row=(lane>>4)*4+reg.
__global__ __launch_bounds__(256, 4) void chamfer_mfma_kernel(
    const short8* __restrict__ afrag, const short8* __restrict__ bfrag,
    int* __restrict__ minsq)
{
    const int lane = threadIdx.x & 63;
    const int wid  = blockIdx.x * 4 + (threadIdx.x >> 6);  // [0,4096)
    const int dir  = wid >> 11;
    const int rem  = wid & 2047;
    const int ag   = rem >> 4;    // A-group [0,128)
    const int bc   = rem & 15;    // B-chunk [0,16)

    const short8* __restrict__ af = afrag + (size_t)dir * NT16 * 64;
    const short8* __restrict__ gsrc = bfrag + (size_t)dir * NT16 * 64
                                            + (size_t)(bc * CPT) * 64;

    short8 a[R];
    #pragma unroll
    for (int r = 0; r < R; ++r)
        a[r] = af[(ag * R + r) * 64 + lane];

    f32x4 m[R];
    #pragma unroll
    for (int r = 0; r < R; ++r)
        m[r] = (f32x4)(FLT_MAX);

    const f32x4 zero = (f32x4)(0.0f);
    #pragma unroll 1
    for (int pp = 0; pp < CPT / 4; ++pp) {          // 16 iterations
        short8 b0 = gsrc[(4 * pp + 0) * 64 + lane];
        short8 b1 = gsrc[(4 * pp + 1) * 64 + lane];
        short8 b2 = gsrc[(4 * pp + 2) * 64 + lane];
        short8 b3 = gsrc[(4 * pp + 3) * 64 + lane];
        #pragma unroll
        for (int r = 0; r < R; ++r) {
            f32x4 c0 = __builtin_amdgcn_mfma_f32_16x16x32_bf16(a[r], b0, zero, 0, 0, 0);
            f32x4 c1 = __builtin_amdgcn_mfma_f32_16x16x32_bf16(a[r], b1, zero, 0, 0, 0);
            #pragma unroll
            for (int i = 0; i < 4; ++i)
                m[r][i] = fminf(m[r][i], fminf(c0[i], c1[i]));   // v_min3_f32
            f32x4 c2 = __builtin_amdgcn_mfma_f32_16x16x32_bf16(a[r], b2, zero, 0, 0, 0);
            f32x4 c3 = __builtin_amdgcn_mfma_f32_16x16x32_bf16(a[r], b3, zero, 0, 0, 0);
            #pragma unroll
            for (int i = 0; i < 4; ++i)
                m[r][i] = fminf(m[r][i], fminf(c2[i], c3[i]));
        }
    }

    // min over the 16 cols: butterfly over lane bits 0..3 (stays in 16-lane group)
    #pragma unroll
    for (int r = 0; r < R; ++r) {
        #pragma unroll
        for (int i = 0; i < 4; ++i) {
            float v = m[r][i];
            v = fminf(v, __shfl_xor(v, 1, 64));
            v = fminf(v, __shfl_xor(v, 2, 64));
            v = fminf(v, __shfl_xor(v, 4, 64));
            v = fminf(v, __shfl_xor(v, 8, 64));
            m[r][i] = v;
        }
    }

    // lanes 0,16,32,48 publish rows (lane>>4)*4+i of each A-tile
    if ((lane & 15) == 0) {
        const int g = lane >> 4;
        #pragma unroll
        for (int r = 0; r < R; ++r) {
            const int at = ag * R + r;
            #pragma unroll
            for (int i = 0; i < 4; ++i) {
                int row = g * 4 + i;
                atomicMin(&minsq[dir * NPTS + at * 16 + row], __float_as_int(m[r][i]));
            }
        }
    }
}

__global__ __launch_bounds__(256) void reduce_kernel(
    const int* __restrict__ minsq, float* __restrict__ out)
{
    float s = 0.f;
    const int4* mv = (const int4*)minsq;   // 2*NPTS/4 = 8192 int4s
    for (int k = blockIdx.x * 256 + threadIdx.x; k < 2 * NPTS / 4; k += gridDim.x * 256) {
        int4 v = mv[k];
        s += sqrtf(fmaxf(__int_as_float(v.x), 0.f))
           + sqrtf(fmaxf(__int_as_float(v.y), 0.f))
           + sqrtf(fmaxf(__int_as_float(v.z), 0.f))
           + sqrtf(fmaxf(__int_as_float(v.w), 0.f));
    }
    for (int off = 32; off; off >>= 1) s += __shfl_down(s, off, 64);
    __shared__ float partial[4];
    if ((threadIdx.x & 63) == 0) partial[threadIdx.x >> 6] = s;
    __syncthreads();
    if (threadIdx.x == 0)
        atomicAdd(out, (partial[0] + partial[1] + partial[2] + partial[3]) * 0.001f);
}

extern "C" void kernel_launch(void* const* d_in, const int* in_sizes, int n_in,
                              void* d_out, int out_size, void* d_ws, size_t ws_size,
                              hipStream_t stream) {
    const float* target = (const float*)d_in[0];  // [16384,3]
    const float* output = (const float*)d_in[1];  // [16384,3]
    float* out = (float*)d_out;

    // ws: afrag 2MB | bfrag 2MB | minsq 128KB
    short8* afrag = (short8*)d_ws;
    short8* bfrag = afrag + 2 * NT16 * 64;
    int* minsq = (int*)(bfrag + 2 * NT16 * 64);

    // 3 nodes: pack (+init), mfma-min, reduce
    pack_kernel<<<2 * NT16 * 64 / 256, 256, 0, stream>>>(
        target, output, afrag, bfrag, minsq, out);
    // 1024 blocks x 4 waves = 4096 waves = 2 dirs * 128 A-groups * 16 B-chunks
    chamfer_mfma_kernel<<<1024, 256, 0, stream>>>(afrag, bfrag, minsq);
    reduce_kernel<<<32, 256, 0, stream>>>(minsq, out);
}

// Round 17
// 89.425 us; speedup vs baseline: 1.1694x; 1.1694x over previous
//
#include <hip/hip_runtime.h>
#include <hip/hip_bf16.h>
#include <cfloat>

#define NPTS 16384
#define NTILES 512          // 32-point tiles per side
#define R 2                 // A-tiles per wave (acc m = 32 regs)
#define BS 16               // B-chunk splits (low bits of bid -> XCD-local L2 reuse)
#define CPT (NTILES / BS)   // 32 B-tiles per chunk

typedef short short8  __attribute__((ext_vector_type(8)));
typedef float f32x16  __attribute__((ext_vector_type(16)));

__device__ inline short bf16s(float x) {
    __hip_bfloat16 h = __float2bfloat16(x);   // RNE
    return *reinterpret_cast<short*>(&h);
}
__device__ inline float bf16f(short s) {
    __hip_bfloat16 h = *reinterpret_cast<__hip_bfloat16*>(&s);
    return __bfloat162float(h);
}

// Build per-tile MFMA fragments (identical math since R9 — verified absmax 0).
// Slot map s = 8*(lane>>5) + j, j in [0,8).
// A row s-values:  [ahx ahy ahz alx aly alz ahx ahy | ahz 1 1 sqa_hi sqa_lo 0 0 0]
// B col s-values:  [bhx bhy bhz bhx bhy bhz blx bly | blz sqb_hi sqb_lo 1 1 0 0 0]
// Sum over s = -2 a.b + |b|^2 + |a|^2 = d^2 (missing only -2*alo*blo ~ 5e-5).
// Also initializes minsq (0x7F7F7F7F) and out[0]=0 (re-poisoned each call).
__global__ __launch_bounds__(256) void pack_kernel(
    const float* __restrict__ target, const float* __restrict__ output,
    short8* __restrict__ afrag, short8* __restrict__ bfrag,
    int* __restrict__ minsq, float* __restrict__ out)
{
    int t = blockIdx.x * 256 + threadIdx.x;   // [0, 2*512*64)
    if (t < 2 * NPTS) minsq[t] = 0x7F7F7F7F;
    if (t == 0) out[0] = 0.0f;

    int lane = t & 63;
    int tile = (t >> 6) & (NTILES - 1);
    int dir  = t >> 15;
    const float* __restrict__ A = dir ? target : output;  // query side
    const float* __restrict__ B = dir ? output : target;  // candidate side
    int p = tile * 32 + (lane & 31);
    int g = lane >> 5;
    int idx = (dir * NTILES + tile) * 64 + lane;

    {
        float x = A[3 * p], y = A[3 * p + 1], z = A[3 * p + 2];
        short hx = bf16s(x), hy = bf16s(y), hz = bf16s(z);
        short lx = bf16s(x - bf16f(hx)), ly = bf16s(y - bf16f(hy)), lz = bf16s(z - bf16f(hz));
        float sq = fmaf(x, x, fmaf(y, y, z * z));
        short sh = bf16s(sq), sl = bf16s(sq - bf16f(sh));
        const short one = 0x3F80;
        short8 loa = { hx, hy, hz, lx, ly, lz, hx, hy };
        short8 hia = { hz, one, one, sh, sl, 0, 0, 0 };
        afrag[idx] = g ? hia : loa;
    }
    {
        float x = B[3 * p], y = B[3 * p + 1], z = B[3 * p + 2];
        float nx = -2.f * x, ny = -2.f * y, nz = -2.f * z;
        short hx = bf16s(nx), hy = bf16s(ny), hz = bf16s(nz);
        short lx = bf16s(nx - bf16f(hx)), ly = bf16s(ny - bf16f(hy)), lz = bf16s(nz - bf16f(hz));
        float sq = fmaf(x, x, fmaf(y, y, z * z));
        short sh = bf16s(sq), sl = bf16s(sq - bf16f(sh));
        const short one = 0x3F80;
        short8 lob = { hx, hy, hz, hx, hy, hz, lx, ly };
        short8 hib = { lz, sh, sl, one, one, 0, 0, 0 };
        bfrag[idx] = g ? hib : lob;
    }
}

// R12 structure verbatim (best measured): 256-thread blocks, R=2, 2-deep
// loads, NO unroll pragma — the compiler unrolls & software-pipelines.
// Each wave: R=2 fixed A-tiles vs a CPT-tile B chunk from L2, fence-free.
// C/D layout (m74/m101): col=lane&31, row=(reg&3)+8*(reg>>2)+4*(lane>>5).
__global__ __launch_bounds__(256, 4) void chamfer_mfma_kernel(
    const short8* __restrict__ afrag, const short8* __restrict__ bfrag,
    int* __restrict__ minsq)
{
    const int lane = threadIdx.x & 63;
    const int wid  = blockIdx.x * 4 + (threadIdx.x >> 6);  // [0,8192)
    const int dir  = wid >> 12;
    const int rem  = wid & 4095;
    const int ag   = rem >> 4;    // A-group [0,256)
    const int bc   = rem & 15;    // B-chunk [0,16) — low bits -> XCD-local

    const short8* __restrict__ af = afrag + (size_t)dir * NTILES * 64;
    const short8* __restrict__ gsrc = bfrag + (size_t)dir * NTILES * 64
                                            + (size_t)(bc * CPT) * 64;

    short8 a[R];
    #pragma unroll
    for (int r = 0; r < R; ++r)
        a[r] = af[(ag * R + r) * 64 + lane];

    f32x16 m[R];
    #pragma unroll
    for (int r = 0; r < R; ++r)
        m[r] = (f32x16)(FLT_MAX);

    const f32x16 zero = (f32x16)(0.0f);
    for (int pp = 0; pp < CPT / 2; ++pp) {          // 16 iterations, 2-deep
        short8 b0 = gsrc[(2 * pp + 0) * 64 + lane];
        short8 b1 = gsrc[(2 * pp + 1) * 64 + lane];
        #pragma unroll
        for (int r = 0; r < R; ++r) {
            f32x16 c0 = __builtin_amdgcn_mfma_f32_32x32x16_bf16(a[r], b0, zero, 0, 0, 0);
            f32x16 c1 = __builtin_amdgcn_mfma_f32_32x32x16_bf16(a[r], b1, zero, 0, 0, 0);
            #pragma unroll
            for (int i = 0; i < 16; ++i)
                m[r][i] = fminf(m[r][i], fminf(c0[i], c1[i]));   // v_min3_f32
        }
    }

    // butterfly min over the 32 cols (xor bits 0..4 stay within each 32-half)
    #pragma unroll
    for (int r = 0; r < R; ++r) {
        #pragma unroll
        for (int i = 0; i < 16; ++i) {
            float v = m[r][i];
            v = fminf(v, __shfl_xor(v, 1, 64));
            v = fminf(v, __shfl_xor(v, 2, 64));
            v = fminf(v, __shfl_xor(v, 4, 64));
            v = fminf(v, __shfl_xor(v, 8, 64));
            v = fminf(v, __shfl_xor(v, 16, 64));
            m[r][i] = v;
        }
    }

    // one lane per 32-half publishes its 16 row-mins (signed-int float order;
    // tiny-negative d^2 -> large-negative int -> wins min -> clamped later)
    if ((lane & 31) == 0) {
        const int g = lane >> 5;
        #pragma unroll
        for (int r = 0; r < R; ++r) {
            const int at = ag * R + r;
            #pragma unroll
            for (int i = 0; i < 16; ++i) {
                int row = (i & 3) + 8 * (i >> 2) + 4 * g;
                atomicMin(&minsq[dir * NPTS + at * 32 + row], __float_as_int(m[r][i]));
            }
        }
    }
}

__global__ __launch_bounds__(256) void reduce_kernel(
    const int* __restrict__ minsq, float* __restrict__ out)
{
    float s = 0.f;
    const int4* mv = (const int4*)minsq;   // 2*NPTS/4 = 8192 int4s
    for (int k = blockIdx.x * 256 + threadIdx.x; k < 2 * NPTS / 4; k += gridDim.x * 256) {
        int4 v = mv[k];
        s += sqrtf(fmaxf(__int_as_float(v.x), 0.f))
           + sqrtf(fmaxf(__int_as_float(v.y), 0.f))
           + sqrtf(fmaxf(__int_as_float(v.z), 0.f))
           + sqrtf(fmaxf(__int_as_float(v.w), 0.f));
    }
    for (int off = 32; off; off >>= 1) s += __shfl_down(s, off, 64);
    __shared__ float partial[4];
    if ((threadIdx.x & 63) == 0) partial[threadIdx.x >> 6] = s;
    __syncthreads();
    if (threadIdx.x == 0)
        atomicAdd(out, (partial[0] + partial[1] + partial[2] + partial[3]) * 0.001f);
}

extern "C" void kernel_launch(void* const* d_in, const int* in_sizes, int n_in,
                              void* d_out, int out_size, void* d_ws, size_t ws_size,
                              hipStream_t stream) {
    const float* target = (const float*)d_in[0];  // [16384,3]
    const float* output = (const float*)d_in[1];  // [16384,3]
    float* out = (float*)d_out;

    // ws: afrag 1MB | bfrag 1MB | minsq 128KB
    short8* afrag = (short8*)d_ws;
    short8* bfrag = afrag + 2 * NTILES * 64;
    int* minsq = (int*)(bfrag + 2 * NTILES * 64);

    // 3 nodes: pack (+init), mfma-min, reduce
    pack_kernel<<<2 * NTILES * 64 / 256, 256, 0, stream>>>(
        target, output, afrag, bfrag, minsq, out);
    // 2048 blocks x 4 waves = 8192 waves = 2 dirs * 256 A-groups * 16 B-chunks
    chamfer_mfma_kernel<<<2048, 256, 0, stream>>>(afrag, bfrag, minsq);
    reduce_kernel<<<32, 256, 0, stream>>>(minsq, out);
}